// Round 3
// baseline (132.939 us; speedup 1.0000x reference)
//
#include <hip/hip_runtime.h>
#include <math.h>

#define Ec 256
#define Sc 512
#define Bc 2
#define Hc 8
#define Dc 32
#define MAXNORM (1.0f - 1e-5f)
#define NEc (Bc * Sc * Ec)
#define KSQ 2                  // K-split for qkv GEMM (nk=2 chunks of 64)
#define KSO 4                  // K-split for proj GEMM (nk=1)
#define NROWS (Bc * Hc * Sc)   // 8192 (b,h,s) rows
#define KT 128                 // fused-attn k-tile
#define NT (Sc / KT)           // 4 tiles

__device__ __forceinline__ float fullWaveSum(float v) {
#pragma unroll
  for (int m = 32; m >= 1; m >>= 1) v += __shfl_xor(v, m, 64);
  return v;
}
__device__ __forceinline__ float halfWaveSum(float v) {
#pragma unroll
  for (int m = 16; m >= 1; m >>= 1) v += __shfl_xor(v, m, 64);
  return v;
}
__device__ __forceinline__ float atanh_fast(float z) {   // z in [0, 1)
  return 0.5f * __logf((1.0f + z) / (1.0f - z));
}
__device__ __forceinline__ float tanh_fast(float a) {    // a >= 0
  float e = __expf(-2.0f * a);
  return (1.0f - e) / (1.0f + e);
}

// ---------------------------------------------------------------------------
// Tiled GEMM partial: O[kz] = X[:, kz*64*nk : (kz+1)*64*nk] @ W[:, same]^T
// Tile 64 rows x 64 cols, 4x8 per thread (1.5 B/FMA), nk K-chunks of 64.
// blk 128. qkv grid 384 blocks, proj 256.
// ---------------------------------------------------------------------------
__global__ __launch_bounds__(128) void gemm_xwt(
    const float* __restrict__ X,
    const float* __restrict__ W0, const float* __restrict__ W1,
    const float* __restrict__ W2,
    float* __restrict__ O0, float* __restrict__ O1, float* __restrict__ O2,
    const int nk) {
  const int tid = threadIdx.x;
  const int bx = blockIdx.x;
  const int by = blockIdx.y;
  const int kz = blockIdx.z;
  const int mat = by >> 2;
  const int cb0 = (by & 3) * 64;
  const int rb0 = bx * 64;
  const int kk0 = kz * 64 * nk;
  const float* __restrict__ W = (mat == 0) ? W0 : (mat == 1) ? W1 : W2;
  float* __restrict__ O = ((mat == 0) ? O0 : (mat == 1) ? O1 : O2) + (size_t)kz * NEc;

  __shared__ float Xs[64][68];   // [k][row]
  __shared__ float Ws[64][68];   // [k][col]

  const int f4 = tid & 15;       // k-quad for staging
  const int sub = tid >> 4;      // 0..7
  const int r4 = tid >> 3;       // 0..15 row-quad
  const int c8 = tid & 7;        // 0..7 col-oct

  float acc[4][8];
#pragma unroll
  for (int i = 0; i < 4; ++i)
#pragma unroll
    for (int j = 0; j < 8; ++j) acc[i][j] = 0.f;

  for (int c = 0; c < nk; ++c) {
    const int kk = kk0 + c * 64;
    __syncthreads();
#pragma unroll
    for (int i = 0; i < 8; ++i) {
      int row = sub + i * 8;
      float4 v = *(const float4*)&X[(size_t)(rb0 + row) * Ec + kk + f4 * 4];
      Xs[f4 * 4 + 0][row] = v.x;
      Xs[f4 * 4 + 1][row] = v.y;
      Xs[f4 * 4 + 2][row] = v.z;
      Xs[f4 * 4 + 3][row] = v.w;
      float4 w = *(const float4*)&W[(size_t)(cb0 + row) * Ec + kk + f4 * 4];
      Ws[f4 * 4 + 0][row] = w.x;
      Ws[f4 * 4 + 1][row] = w.y;
      Ws[f4 * 4 + 2][row] = w.z;
      Ws[f4 * 4 + 3][row] = w.w;
    }
    __syncthreads();
#pragma unroll 8
    for (int k = 0; k < 64; ++k) {
      float4 a = *(const float4*)&Xs[k][r4 * 4];
      float4 b0 = *(const float4*)&Ws[k][c8 * 8];
      float4 b1 = *(const float4*)&Ws[k][c8 * 8 + 4];
      float av[4] = {a.x, a.y, a.z, a.w};
      float bv[8] = {b0.x, b0.y, b0.z, b0.w, b1.x, b1.y, b1.z, b1.w};
#pragma unroll
      for (int i = 0; i < 4; ++i)
#pragma unroll
        for (int j = 0; j < 8; ++j) acc[i][j] = fmaf(av[i], bv[j], acc[i][j]);
    }
  }
#pragma unroll
  for (int i = 0; i < 4; ++i) {
    float4 o0 = make_float4(acc[i][0], acc[i][1], acc[i][2], acc[i][3]);
    float4 o1 = make_float4(acc[i][4], acc[i][5], acc[i][6], acc[i][7]);
    *(float4*)&O[(size_t)(rb0 + r4 * 4 + i) * Ec + cb0 + c8 * 8] = o0;
    *(float4*)&O[(size_t)(rb0 + r4 * 4 + i) * Ec + cb0 + c8 * 8 + 4] = o1;
  }
}

// ---------------------------------------------------------------------------
// Per-row hyp_linear epilogue for q/k/v (sums the KSQ K-split partials)
// ---------------------------------------------------------------------------
__global__ __launch_bounds__(256) void qkv_stats(
    const float* __restrict__ x,
    const float* __restrict__ mxq, const float* __restrict__ mxk,
    const float* __restrict__ mxv,
    const float* __restrict__ bq, const float* __restrict__ bk,
    const float* __restrict__ bv,
    float* __restrict__ qo, float* __restrict__ ko, float* __restrict__ lvo,
    float* __restrict__ qno, float* __restrict__ kno) {
  const int t = threadIdx.x;
  const int row = blockIdx.x;
  const int b = row >> 9;
  const int s = row & (Sc - 1);
  const size_t idx = (size_t)row * Ec + t;
  const float xv = x[idx];
  float mq = 0.f, mk = 0.f, mv = 0.f;
#pragma unroll
  for (int p = 0; p < KSQ; ++p) {
    mq += mxq[idx + (size_t)p * NEc];
    mk += mxk[idx + (size_t)p * NEc];
    mv += mxv[idx + (size_t)p * NEc];
  }
  const float bb[3] = {bq[t], bk[t], bv[t]};
  const float mvals[3] = {mq, mk, mv};

  float vals[10] = {xv * xv,
                    mq * mq, mq * bb[0], bb[0] * bb[0],
                    mk * mk, mk * bb[1], bb[1] * bb[1],
                    mv * mv, mv * bb[2], bb[2] * bb[2]};
  __shared__ float red[10][4];
  __shared__ float fin[10];
#pragma unroll
  for (int i = 0; i < 10; ++i) {
    float v = fullWaveSum(vals[i]);
    if ((t & 63) == 0) red[i][t >> 6] = v;
  }
  __syncthreads();
  if (t < 10) fin[t] = red[t][0] + red[t][1] + red[t][2] + red[t][3];
  __syncthreads();

  const float x2 = fin[0];
  const float xn = sqrtf(fmaxf(x2, 1e-15f));
  const float at = atanh_fast(fminf(xn, MAXNORM));  // SC = 1
  const int h = t >> 5;

#pragma unroll
  for (int m = 0; m < 3; ++m) {
    float mx2 = fin[1 + 3 * m];
    float mxb = fin[2 + 3 * m];
    float b2 = fin[3 + 3 * m];
    float mxn = sqrtf(fmaxf(mx2, 1e-15f));
    float scl = tanh_fast((mxn / xn) * at) / mxn;
    float mvv = scl * mvals[m];
    float X2 = scl * scl * mx2;
    float XY = scl * mxb;
    float numc = 1.0f + 2.0f * XY + b2;
    float den = 1.0f + 2.0f * XY + X2 * b2 + 1e-15f;
    float res = (numc * mvv + (1.0f - X2) * bb[m]) / den;
    if (m < 2) {
      res = fminf(res, MAXNORM);                 // elementwise clamp_max
      float s2 = halfWaveSum(res * res);         // per-head ||.||^2 (C=1)
      if (m == 0) {
        qo[idx] = res;
        if ((t & 31) == 0) qno[(b * Hc + h) * Sc + s] = s2;
      } else {
        ko[idx] = res;
        if ((t & 31) == 0) kno[(b * Hc + h) * Sc + s] = s2;
      }
    } else {
      float vn2 = halfWaveSum(res * res);
      float vn = sqrtf(fmaxf(vn2, 1e-15f));
      float f = atanh_fast(fminf(vn, MAXNORM)) / vn;  // logmap0 factor
      lvo[idx] = f * res;
    }
  }
}

// ---------------------------------------------------------------------------
// Fused attention v3: per block = 32 q-rows of one (b,h); 4 k-tiles of 128.
// QK: 4 rows x 4 cols per thread, Q in registers (128 VGPR) -> 1 B/FMA.
// PV: 4 rows x 8 dims x chunked j-slices -> 1.5 B/FMA.
// Kst/Pst alias the end-phase accm merge buffer (union) -> 56 KB LDS.
// grid (16 sq-tiles, 16 bh) = 256 blocks, blk 256.
// ---------------------------------------------------------------------------
__global__ __launch_bounds__(256) void attn_fused(
    const float* __restrict__ q, const float* __restrict__ k,
    const float* __restrict__ lv, const float* __restrict__ qn,
    const float* __restrict__ kn, const float* __restrict__ hs,
    float* __restrict__ out) {
  const int tid = threadIdx.x;
  const int sq0 = blockIdx.x * 32;
  const int bh = blockIdx.y;
  const int b = bh >> 3;
  const int h = bh & 7;

  __shared__ float Qst[32][36];      // q staging, then to regs
  __shared__ float LVs[128][36];     // [j][d] row-major lv-tile
  __shared__ float knS[128];         // kn tile; reused as dens[32] at end
  union SMU {
    struct { float Kst[32][132]; float Pst[32][132]; } a;  // 33.8 KB
    struct { float accm[32 * 260]; } m;                    // 33.3 KB
  };
  __shared__ __align__(16) SMU u;

  const int r4 = tid >> 5;           // 0..7: rows r4*4..+3 (QK and PV)
  const int c4 = tid & 31;           // QK col-quad
  const int dgrp = (tid >> 3) & 3;   // PV d-oct (8 dims)
  const int jsl = tid & 7;           // PV j-slice (chunked: j = ch*32+jsl*4+jj)
  const int rr = tid >> 1;           // staging row 0..127
  const int half = tid & 1;

  // ---- stage Q, move 4 rows x 32 d to registers ----
  {
    int qr = tid >> 3, dqq = tid & 7;
    *(float4*)&Qst[qr][dqq * 4] =
        *(const float4*)&q[(size_t)(b * Sc + sq0 + qr) * Ec + h * Dc + dqq * 4];
  }
  __syncthreads();
  float4 qv0[8], qv1[8], qv2[8], qv3[8];
#pragma unroll
  for (int fd = 0; fd < 8; ++fd) {
    qv0[fd] = *(const float4*)&Qst[r4 * 4 + 0][fd * 4];
    qv1[fd] = *(const float4*)&Qst[r4 * 4 + 1][fd * 4];
    qv2[fd] = *(const float4*)&Qst[r4 * 4 + 2][fd * 4];
    qv3[fd] = *(const float4*)&Qst[r4 * 4 + 3][fd * 4];
  }
  float q2r[4], omq[4];
#pragma unroll
  for (int i = 0; i < 4; ++i) {
    q2r[i] = qn[bh * Sc + sq0 + r4 * 4 + i];
    omq[i] = 1.0f - q2r[i];
  }
  const float sinv = -1.0f / (hs[h] * sqrtf((float)Dc));

  float4 acc0[4], acc1[4];
#pragma unroll
  for (int i = 0; i < 4; ++i) {
    acc0[i] = make_float4(0.f, 0.f, 0.f, 0.f);
    acc1[i] = make_float4(0.f, 0.f, 0.f, 0.f);
  }
  float dprt[4] = {0.f, 0.f, 0.f, 0.f};

  for (int t = 0; t < NT; ++t) {
    const int j0g = t * KT;
    __syncthreads();   // prior tile's QK/PV reads complete
    // ---- stage K (transposed) + LV (row-major) + kn ----
    {
      const size_t gbase = (size_t)(b * Sc + j0g + rr) * Ec + h * Dc;
#pragma unroll
      for (int i2 = 0; i2 < 4; ++i2) {
        const int dqq = half * 4 + i2;
        float4 kv = *(const float4*)&k[gbase + dqq * 4];
        u.a.Kst[dqq * 4 + 0][rr] = kv.x;
        u.a.Kst[dqq * 4 + 1][rr] = kv.y;
        u.a.Kst[dqq * 4 + 2][rr] = kv.z;
        u.a.Kst[dqq * 4 + 3][rr] = kv.w;
        *(float4*)&LVs[rr][dqq * 4] = *(const float4*)&lv[gbase + dqq * 4];
      }
      if (tid < 128) knS[tid] = kn[bh * Sc + j0g + tid];
    }
    __syncthreads();   // staged tile visible

    // ---- QK: 4 rows x 4 cols over d=32 (1 B/FMA) ----
    float p0[4] = {0.f, 0.f, 0.f, 0.f};
    float p1[4] = {0.f, 0.f, 0.f, 0.f};
    float p2[4] = {0.f, 0.f, 0.f, 0.f};
    float p3[4] = {0.f, 0.f, 0.f, 0.f};
#pragma unroll
    for (int fd = 0; fd < 8; ++fd) {
      float4 k0 = *(const float4*)&u.a.Kst[fd * 4 + 0][c4 * 4];
      float4 k1 = *(const float4*)&u.a.Kst[fd * 4 + 1][c4 * 4];
      float4 k2 = *(const float4*)&u.a.Kst[fd * 4 + 2][c4 * 4];
      float4 k3 = *(const float4*)&u.a.Kst[fd * 4 + 3][c4 * 4];
#define QKROW(A, P)                                                   \
      P[0] = fmaf(A.x, k0.x, P[0]); P[0] = fmaf(A.y, k1.x, P[0]);     \
      P[0] = fmaf(A.z, k2.x, P[0]); P[0] = fmaf(A.w, k3.x, P[0]);     \
      P[1] = fmaf(A.x, k0.y, P[1]); P[1] = fmaf(A.y, k1.y, P[1]);     \
      P[1] = fmaf(A.z, k2.y, P[1]); P[1] = fmaf(A.w, k3.y, P[1]);     \
      P[2] = fmaf(A.x, k0.z, P[2]); P[2] = fmaf(A.y, k1.z, P[2]);     \
      P[2] = fmaf(A.z, k2.z, P[2]); P[2] = fmaf(A.w, k3.z, P[2]);     \
      P[3] = fmaf(A.x, k0.w, P[3]); P[3] = fmaf(A.y, k1.w, P[3]);     \
      P[3] = fmaf(A.z, k2.w, P[3]); P[3] = fmaf(A.w, k3.w, P[3]);
      { float4 a = qv0[fd]; QKROW(a, p0) }
      { float4 a = qv1[fd]; QKROW(a, p1) }
      { float4 a = qv2[fd]; QKROW(a, p2) }
      { float4 a = qv3[fd]; QKROW(a, p3) }
#undef QKROW
    }

    // ---- epilogue: hyperbolic distance -> p = z^sinv, write Pst, den ----
    float4 k2v = *(const float4*)&knS[c4 * 4];
    const float kk2[4] = {k2v.x, k2v.y, k2v.z, k2v.w};
#define EPIROW(P, RIDX)                                                     \
    {                                                                       \
      float po[4];                                                          \
      _Pragma("unroll")                                                     \
      for (int j = 0; j < 4; ++j) {                                         \
        const float k2 = kk2[j];                                            \
        const float kq = P[j];                                              \
        const float omk = 1.0f - k2;                                        \
        float s2x2 = fmaf(-4.0f, kq, 2.0f * k2 + 2.0f * q2r[RIDX]);         \
        float dden = fmaf(k2, q2r[RIDX], fmaf(-2.0f, kq, 1.0f)) + 1e-15f;   \
        float Pd = fmaf(dden, omk * omq[RIDX], 1e-20f);                     \
        float rp = __builtin_amdgcn_rcpf(Pd);                               \
        float tt = fmaxf(s2x2 * rp, 1e-7f);                                 \
        float z = (1.0f + tt) + sqrtf(fmaf(tt, tt, tt + tt));               \
        po[j] = __builtin_amdgcn_exp2f(sinv * __builtin_amdgcn_logf(z));    \
      }                                                                     \
      dprt[RIDX] += (po[0] + po[1]) + (po[2] + po[3]);                      \
      *(float4*)&u.a.Pst[r4 * 4 + RIDX][c4 * 4] =                           \
          make_float4(po[0], po[1], po[2], po[3]);                          \
    }
    EPIROW(p0, 0)
    EPIROW(p1, 1)
    EPIROW(p2, 2)
    EPIROW(p3, 3)
#undef EPIROW
    __syncthreads();   // Pst complete

    // ---- PV: acc[4 rows][8 dims] += P[rows][j] * LV[j][dims] (1.5 B/FMA) ----
#pragma unroll
    for (int ch = 0; ch < 4; ++ch) {
      const int j0 = ch * 32 + jsl * 4;
      float4 pr0 = *(const float4*)&u.a.Pst[r4 * 4 + 0][j0];
      float4 pr1 = *(const float4*)&u.a.Pst[r4 * 4 + 1][j0];
      float4 pr2 = *(const float4*)&u.a.Pst[r4 * 4 + 2][j0];
      float4 pr3 = *(const float4*)&u.a.Pst[r4 * 4 + 3][j0];
      float4 la0 = *(const float4*)&LVs[j0 + 0][dgrp * 8];
      float4 lb0 = *(const float4*)&LVs[j0 + 0][dgrp * 8 + 4];
      float4 la1 = *(const float4*)&LVs[j0 + 1][dgrp * 8];
      float4 lb1 = *(const float4*)&LVs[j0 + 1][dgrp * 8 + 4];
      float4 la2 = *(const float4*)&LVs[j0 + 2][dgrp * 8];
      float4 lb2 = *(const float4*)&LVs[j0 + 2][dgrp * 8 + 4];
      float4 la3 = *(const float4*)&LVs[j0 + 3][dgrp * 8];
      float4 lb3 = *(const float4*)&LVs[j0 + 3][dgrp * 8 + 4];
#define PVROW(PR, I)                                                    \
      acc0[I].x = fmaf(PR.x, la0.x, acc0[I].x);                         \
      acc0[I].y = fmaf(PR.x, la0.y, acc0[I].y);                         \
      acc0[I].z = fmaf(PR.x, la0.z, acc0[I].z);                         \
      acc0[I].w = fmaf(PR.x, la0.w, acc0[I].w);                         \
      acc1[I].x = fmaf(PR.x, lb0.x, acc1[I].x);                         \
      acc1[I].y = fmaf(PR.x, lb0.y, acc1[I].y);                         \
      acc1[I].z = fmaf(PR.x, lb0.z, acc1[I].z);                         \
      acc1[I].w = fmaf(PR.x, lb0.w, acc1[I].w);                         \
      acc0[I].x = fmaf(PR.y, la1.x, acc0[I].x);                         \
      acc0[I].y = fmaf(PR.y, la1.y, acc0[I].y);                         \
      acc0[I].z = fmaf(PR.y, la1.z, acc0[I].z);                         \
      acc0[I].w = fmaf(PR.y, la1.w, acc0[I].w);                         \
      acc1[I].x = fmaf(PR.y, lb1.x, acc1[I].x);                         \
      acc1[I].y = fmaf(PR.y, lb1.y, acc1[I].y);                         \
      acc1[I].z = fmaf(PR.y, lb1.z, acc1[I].z);                         \
      acc1[I].w = fmaf(PR.y, lb1.w, acc1[I].w);                         \
      acc0[I].x = fmaf(PR.z, la2.x, acc0[I].x);                         \
      acc0[I].y = fmaf(PR.z, la2.y, acc0[I].y);                         \
      acc0[I].z = fmaf(PR.z, la2.z, acc0[I].z);                         \
      acc0[I].w = fmaf(PR.z, la2.w, acc0[I].w);                         \
      acc1[I].x = fmaf(PR.z, lb2.x, acc1[I].x);                         \
      acc1[I].y = fmaf(PR.z, lb2.y, acc1[I].y);                         \
      acc1[I].z = fmaf(PR.z, lb2.z, acc1[I].z);                         \
      acc1[I].w = fmaf(PR.z, lb2.w, acc1[I].w);                         \
      acc0[I].x = fmaf(PR.w, la3.x, acc0[I].x);                         \
      acc0[I].y = fmaf(PR.w, la3.y, acc0[I].y);                         \
      acc0[I].z = fmaf(PR.w, la3.z, acc0[I].z);                         \
      acc0[I].w = fmaf(PR.w, la3.w, acc0[I].w);                         \
      acc1[I].x = fmaf(PR.w, lb3.x, acc1[I].x);                         \
      acc1[I].y = fmaf(PR.w, lb3.y, acc1[I].y);                         \
      acc1[I].z = fmaf(PR.w, lb3.z, acc1[I].z);                         \
      acc1[I].w = fmaf(PR.w, lb3.w, acc1[I].w);
      PVROW(pr0, 0)
      PVROW(pr1, 1)
      PVROW(pr2, 2)
      PVROW(pr3, 3)
#undef PVROW
    }
    // no trailing barrier: next iteration's top barrier orders restaging
  }

  // ---- switch union to merge buffer ----
  __syncthreads();   // last PV reads of Pst done
#pragma unroll
  for (int i = 0; i < 4; ++i) {
    *(float4*)&u.m.accm[(r4 * 4 + i) * 260 + jsl * 32 + dgrp * 8] = acc0[i];
    *(float4*)&u.m.accm[(r4 * 4 + i) * 260 + jsl * 32 + dgrp * 8 + 4] = acc1[i];
  }
  // denominator: reduce dprt over the 32 c4-lanes of each half-wave
  float ds0 = halfWaveSum(dprt[0]);
  float ds1 = halfWaveSum(dprt[1]);
  float ds2 = halfWaveSum(dprt[2]);
  float ds3 = halfWaveSum(dprt[3]);
  if (c4 == 0) {
    knS[r4 * 4 + 0] = ds0;   // knS reused as dens[32]
    knS[r4 * 4 + 1] = ds1;
    knS[r4 * 4 + 2] = ds2;
    knS[r4 * 4 + 3] = ds3;
  }
  __syncthreads();

  // ---- merge 8 j-slice partials, normalize, expmap0, store ----
  const int row = tid >> 3;      // 0..31
  const int dseg = tid & 7;      // 0..7, 4 dims each
  float4 o = make_float4(0.f, 0.f, 0.f, 0.f);
#pragma unroll
  for (int g = 0; g < 8; ++g) {
    float4 a = *(const float4*)&u.m.accm[row * 260 + g * 32 + dseg * 4];
    o.x += a.x; o.y += a.y; o.z += a.z; o.w += a.w;
  }
  const float li = 1.0f / knS[row];
  o.x *= li; o.y *= li; o.z *= li; o.w *= li;
  float un2 = fmaf(o.x, o.x, fmaf(o.y, o.y, fmaf(o.z, o.z, o.w * o.w)));
  un2 += __shfl_xor(un2, 4, 64);
  un2 += __shfl_xor(un2, 2, 64);
  un2 += __shfl_xor(un2, 1, 64);
  float un = sqrtf(fmaxf(un2, 1e-15f));
  float f = tanh_fast(un) / un;        // expmap0 factor (SC = 1)
  o.x *= f; o.y *= f; o.z *= f; o.w *= f;
  *(float4*)&out[(size_t)(b * Sc + sq0 + row) * Ec + h * Dc + dseg * 4] = o;
}

// ---------------------------------------------------------------------------
// Per-row hyp_linear epilogue for the output projection (sums KSO partials)
// ---------------------------------------------------------------------------
__global__ __launch_bounds__(256) void proj_stats(
    const float* __restrict__ xin, const float* __restrict__ mx,
    const float* __restrict__ bo, float* __restrict__ out) {
  const int t = threadIdx.x;
  const int row = blockIdx.x;
  const size_t idx = (size_t)row * Ec + t;
  const float xv = xin[idx];
  float m = 0.f;
#pragma unroll
  for (int p = 0; p < KSO; ++p) m += mx[idx + (size_t)p * NEc];
  const float bb = bo[t];
  float vals[4] = {xv * xv, m * m, m * bb, bb * bb};
  __shared__ float red[4][4];
  __shared__ float fin[4];
#pragma unroll
  for (int i = 0; i < 4; ++i) {
    float v = fullWaveSum(vals[i]);
    if ((t & 63) == 0) red[i][t >> 6] = v;
  }
  __syncthreads();
  if (t < 4) fin[t] = red[t][0] + red[t][1] + red[t][2] + red[t][3];
  __syncthreads();

  float x2 = fin[0], mx2 = fin[1], mxb = fin[2], b2 = fin[3];
  float xn = sqrtf(fmaxf(x2, 1e-15f));
  float mxn = sqrtf(fmaxf(mx2, 1e-15f));
  float scl = tanh_fast((mxn / xn) * atanh_fast(fminf(xn, MAXNORM))) / mxn;
  float mvv = scl * m;
  float X2 = scl * scl * mx2;
  float XY = scl * mxb;
  float numc = 1.0f + 2.0f * XY + b2;
  float den = 1.0f + 2.0f * XY + X2 * b2 + 1e-15f;
  out[idx] = (numc * mvv + (1.0f - X2) * bb) / den;
}

extern "C" void kernel_launch(void* const* d_in, const int* in_sizes, int n_in,
                              void* d_out, int out_size, void* d_ws, size_t ws_size,
                              hipStream_t stream) {
  (void)in_sizes; (void)n_in; (void)out_size; (void)ws_size;
  const float* x  = (const float*)d_in[0];
  const float* Wq = (const float*)d_in[1];
  const float* bq = (const float*)d_in[2];
  const float* Wk = (const float*)d_in[3];
  const float* bk = (const float*)d_in[4];
  const float* Wv = (const float*)d_in[5];
  const float* bv = (const float*)d_in[6];
  const float* Wo = (const float*)d_in[7];
  const float* bo = (const float*)d_in[8];
  const float* hs = (const float*)d_in[9];

  float* ws = (float*)d_ws;
  const int NE = NEc;            // 262144
  const int NH = NROWS;          // 8192
  float* mxq = ws;               // KSQ*NE partials each
  float* mxk = mxq + KSQ * NE;
  float* mxv = mxk + KSQ * NE;
  float* mxo = mxv + KSQ * NE;   // KSO*NE partials
  float* qb  = mxo + KSO * NE;
  float* kb  = qb + NE;
  float* lvb = kb + NE;
  float* aob = lvb + NE;
  float* qnb = aob + NE;
  float* knb = qnb + NH;

  const int M = Bc * Sc;  // 1024 rows

  gemm_xwt<<<dim3(M / 64, 12, KSQ), 128, 0, stream>>>(x, Wq, Wk, Wv,
                                                      mxq, mxk, mxv, 2);
  qkv_stats<<<M, 256, 0, stream>>>(x, mxq, mxk, mxv, bq, bk, bv,
                                   qb, kb, lvb, qnb, knb);
  attn_fused<<<dim3(16, 16), 256, 0, stream>>>(qb, kb, lvb, qnb, knb, hs, aob);
  gemm_xwt<<<dim3(M / 64, 4, KSO), 128, 0, stream>>>(aob, Wo, Wo, Wo,
                                                     mxo, mxo, mxo, 1);
  proj_stats<<<M, 256, 0, stream>>>(aob, mxo, bo, (float*)d_out);
}

// Round 4
// 122.368 us; speedup vs baseline: 1.0864x; 1.0864x over previous
//
#include <hip/hip_runtime.h>
#include <math.h>

#define Ec 256
#define Sc 512
#define Bc 2
#define Hc 8
#define Dc 32
#define MAXNORM (1.0f - 1e-5f)
#define NEc (Bc * Sc * Ec)
#define KSQ 4                  // K-split for qkv GEMM (4 chunks of 64, nk=1)
#define KSO 4                  // K-split for proj GEMM (nk=1)
#define NROWS (Bc * Hc * Sc)   // 8192 (b,h,s) rows
#define KT 128                 // fused-attn k-tile
#define NT (Sc / KT)           // 4 tiles

__device__ __forceinline__ float fullWaveSum(float v) {
#pragma unroll
  for (int m = 32; m >= 1; m >>= 1) v += __shfl_xor(v, m, 64);
  return v;
}
__device__ __forceinline__ float halfWaveSum(float v) {
#pragma unroll
  for (int m = 16; m >= 1; m >>= 1) v += __shfl_xor(v, m, 64);
  return v;
}
__device__ __forceinline__ float atanh_fast(float z) {   // z in [0, 1)
  return 0.5f * __logf((1.0f + z) / (1.0f - z));
}
__device__ __forceinline__ float tanh_fast(float a) {    // a >= 0
  float e = __expf(-2.0f * a);
  return (1.0f - e) / (1.0f + e);
}

// ---------------------------------------------------------------------------
// Tiled GEMM partial: O[kz] = X[:, kz*64 : kz*64+64] @ W[:, same]^T  (nk=1)
// Tile 64 rows x 64 cols, 4x8 per thread (1.5 B/FMA). blk 128.
// qkv grid 16x12x4 = 768 blocks (3/CU balanced); proj 16x4x4 = 256.
// ---------------------------------------------------------------------------
__global__ __launch_bounds__(128) void gemm_xwt(
    const float* __restrict__ X,
    const float* __restrict__ W0, const float* __restrict__ W1,
    const float* __restrict__ W2,
    float* __restrict__ O0, float* __restrict__ O1, float* __restrict__ O2,
    const int nk) {
  const int tid = threadIdx.x;
  const int bx = blockIdx.x;
  const int by = blockIdx.y;
  const int kz = blockIdx.z;
  const int mat = by >> 2;
  const int cb0 = (by & 3) * 64;
  const int rb0 = bx * 64;
  const int kk0 = kz * 64 * nk;
  const float* __restrict__ W = (mat == 0) ? W0 : (mat == 1) ? W1 : W2;
  float* __restrict__ O = ((mat == 0) ? O0 : (mat == 1) ? O1 : O2) + (size_t)kz * NEc;

  __shared__ float Xs[64][68];   // [k][row]
  __shared__ float Ws[64][68];   // [k][col]

  const int f4 = tid & 15;       // k-quad for staging
  const int sub = tid >> 4;      // 0..7
  const int r4 = tid >> 3;       // 0..15 row-quad
  const int c8 = tid & 7;        // 0..7 col-oct

  float acc[4][8];
#pragma unroll
  for (int i = 0; i < 4; ++i)
#pragma unroll
    for (int j = 0; j < 8; ++j) acc[i][j] = 0.f;

  for (int c = 0; c < nk; ++c) {
    const int kk = kk0 + c * 64;
    __syncthreads();
#pragma unroll
    for (int i = 0; i < 8; ++i) {
      int row = sub + i * 8;
      float4 v = *(const float4*)&X[(size_t)(rb0 + row) * Ec + kk + f4 * 4];
      Xs[f4 * 4 + 0][row] = v.x;
      Xs[f4 * 4 + 1][row] = v.y;
      Xs[f4 * 4 + 2][row] = v.z;
      Xs[f4 * 4 + 3][row] = v.w;
      float4 w = *(const float4*)&W[(size_t)(cb0 + row) * Ec + kk + f4 * 4];
      Ws[f4 * 4 + 0][row] = w.x;
      Ws[f4 * 4 + 1][row] = w.y;
      Ws[f4 * 4 + 2][row] = w.z;
      Ws[f4 * 4 + 3][row] = w.w;
    }
    __syncthreads();
#pragma unroll 8
    for (int k = 0; k < 64; ++k) {
      float4 a = *(const float4*)&Xs[k][r4 * 4];
      float4 b0 = *(const float4*)&Ws[k][c8 * 8];
      float4 b1 = *(const float4*)&Ws[k][c8 * 8 + 4];
      float av[4] = {a.x, a.y, a.z, a.w};
      float bv[8] = {b0.x, b0.y, b0.z, b0.w, b1.x, b1.y, b1.z, b1.w};
#pragma unroll
      for (int i = 0; i < 4; ++i)
#pragma unroll
        for (int j = 0; j < 8; ++j) acc[i][j] = fmaf(av[i], bv[j], acc[i][j]);
    }
  }
#pragma unroll
  for (int i = 0; i < 4; ++i) {
    float4 o0 = make_float4(acc[i][0], acc[i][1], acc[i][2], acc[i][3]);
    float4 o1 = make_float4(acc[i][4], acc[i][5], acc[i][6], acc[i][7]);
    *(float4*)&O[(size_t)(rb0 + r4 * 4 + i) * Ec + cb0 + c8 * 8] = o0;
    *(float4*)&O[(size_t)(rb0 + r4 * 4 + i) * Ec + cb0 + c8 * 8 + 4] = o1;
  }
}

// ---------------------------------------------------------------------------
// Per-row hyp_linear epilogue for q/k/v (sums the KSQ K-split partials)
// ---------------------------------------------------------------------------
__global__ __launch_bounds__(256) void qkv_stats(
    const float* __restrict__ x,
    const float* __restrict__ mxq, const float* __restrict__ mxk,
    const float* __restrict__ mxv,
    const float* __restrict__ bq, const float* __restrict__ bk,
    const float* __restrict__ bv,
    float* __restrict__ qo, float* __restrict__ ko, float* __restrict__ lvo,
    float* __restrict__ qno, float* __restrict__ kno) {
  const int t = threadIdx.x;
  const int row = blockIdx.x;
  const int b = row >> 9;
  const int s = row & (Sc - 1);
  const size_t idx = (size_t)row * Ec + t;
  const float xv = x[idx];
  float mq = 0.f, mk = 0.f, mv = 0.f;
#pragma unroll
  for (int p = 0; p < KSQ; ++p) {
    mq += mxq[idx + (size_t)p * NEc];
    mk += mxk[idx + (size_t)p * NEc];
    mv += mxv[idx + (size_t)p * NEc];
  }
  const float bb[3] = {bq[t], bk[t], bv[t]};
  const float mvals[3] = {mq, mk, mv};

  float vals[10] = {xv * xv,
                    mq * mq, mq * bb[0], bb[0] * bb[0],
                    mk * mk, mk * bb[1], bb[1] * bb[1],
                    mv * mv, mv * bb[2], bb[2] * bb[2]};
  __shared__ float red[10][4];
  __shared__ float fin[10];
#pragma unroll
  for (int i = 0; i < 10; ++i) {
    float v = fullWaveSum(vals[i]);
    if ((t & 63) == 0) red[i][t >> 6] = v;
  }
  __syncthreads();
  if (t < 10) fin[t] = red[t][0] + red[t][1] + red[t][2] + red[t][3];
  __syncthreads();

  const float x2 = fin[0];
  const float xn = sqrtf(fmaxf(x2, 1e-15f));
  const float at = atanh_fast(fminf(xn, MAXNORM));  // SC = 1
  const int h = t >> 5;

#pragma unroll
  for (int m = 0; m < 3; ++m) {
    float mx2 = fin[1 + 3 * m];
    float mxb = fin[2 + 3 * m];
    float b2 = fin[3 + 3 * m];
    float mxn = sqrtf(fmaxf(mx2, 1e-15f));
    float scl = tanh_fast((mxn / xn) * at) / mxn;
    float mvv = scl * mvals[m];
    float X2 = scl * scl * mx2;
    float XY = scl * mxb;
    float numc = 1.0f + 2.0f * XY + b2;
    float den = 1.0f + 2.0f * XY + X2 * b2 + 1e-15f;
    float res = (numc * mvv + (1.0f - X2) * bb[m]) / den;
    if (m < 2) {
      res = fminf(res, MAXNORM);                 // elementwise clamp_max
      float s2 = halfWaveSum(res * res);         // per-head ||.||^2 (C=1)
      if (m == 0) {
        qo[idx] = res;
        if ((t & 31) == 0) qno[(b * Hc + h) * Sc + s] = s2;
      } else {
        ko[idx] = res;
        if ((t & 31) == 0) kno[(b * Hc + h) * Sc + s] = s2;
      }
    } else {
      float vn2 = halfWaveSum(res * res);
      float vn = sqrtf(fmaxf(vn2, 1e-15f));
      float f = atanh_fast(fminf(vn, MAXNORM)) / vn;  // logmap0 factor
      lvo[idx] = f * res;
    }
  }
}

// ---------------------------------------------------------------------------
// Fused attention v2 (proven best): per block = 16 q-rows of one (b,h);
// 4 k-tiles of 128. QK: Kst transposed, Q in regs (2 rows x 32d) -> 2 B/FMA.
// PV: js/rg/dq slicing, float4 x float4, accm merge -> 2 B/FMA.
// grid (32 sq-tiles, 16 bh) = 512 blocks, blk 256, LDS 62 KB (2 blk/CU).
// ---------------------------------------------------------------------------
__global__ __launch_bounds__(256, 2) void attn_fused(
    const float* __restrict__ q, const float* __restrict__ k,
    const float* __restrict__ lv, const float* __restrict__ qn,
    const float* __restrict__ kn, const float* __restrict__ hs,
    float* __restrict__ out) {
  const int tid = threadIdx.x;
  const int sq0 = blockIdx.x * 16;
  const int bh = blockIdx.y;
  const int b = bh >> 3;
  const int h = bh & 7;

  __shared__ float Qst[16][36];      // q staging (row-major), then to regs
  __shared__ float Kst[32][132];     // [d][col] transposed k-tile
  __shared__ float LVs[128][36];     // [j][d] row-major lv-tile
  __shared__ float Pst[16][132];     // [r][j] p-tile
  __shared__ float knS[128];
  __shared__ float accm[16][8][32];  // [row][js][d] PV partial merge
  __shared__ float lsb[16][9];       // [row][js] denominator partials

  // QK mapping: 2 rows x 4 cols per thread
  const int r2 = tid >> 5;           // 0..7 -> rows 2*r2, 2*r2+1
  const int c4 = tid & 31;           // 0..31 -> cols c4*4..+3
  // PV mapping: 4 rows x 4 dims x 16 j per thread
  const int js = tid >> 5;           // 0..7 j-slices of 16
  const int rg = (tid >> 3) & 3;     // row-quad
  const int dq = tid & 7;            // dim-quad
  // staging: row rr, dim-half
  const int rr = tid >> 1;           // 0..127
  const int half = tid & 1;

  // ---- stage Q tile, move to registers ----
  if (tid < 128) {
    int qr = tid >> 3, dqq = tid & 7;
    *(float4*)&Qst[qr][dqq * 4] =
        *(const float4*)&q[(size_t)(b * Sc + sq0 + qr) * Ec + h * Dc + dqq * 4];
  }
  __syncthreads();
  float4 qv0[8], qv1[8];
#pragma unroll
  for (int fd = 0; fd < 8; ++fd) {
    qv0[fd] = *(const float4*)&Qst[2 * r2 + 0][fd * 4];
    qv1[fd] = *(const float4*)&Qst[2 * r2 + 1][fd * 4];
  }
  const float q20 = qn[bh * Sc + sq0 + 2 * r2];
  const float q21 = qn[bh * Sc + sq0 + 2 * r2 + 1];
  const float omq0 = 1.0f - q20;
  const float omq1 = 1.0f - q21;
  const float sinv = -1.0f / (hs[h] * sqrtf((float)Dc));

  float4 acc[4];
#pragma unroll
  for (int i = 0; i < 4; ++i) acc[i] = make_float4(0.f, 0.f, 0.f, 0.f);
  float lsum4[4] = {0.f, 0.f, 0.f, 0.f};

  for (int t = 0; t < NT; ++t) {
    const int j0g = t * KT;
    __syncthreads();   // prior tile's QK/PV reads of Kst/LVs/knS complete
    // ---- stage K (transposed) + LV (row-major) + kn ----
    {
      const size_t gbase = (size_t)(b * Sc + j0g + rr) * Ec + h * Dc;
#pragma unroll
      for (int i = 0; i < 4; ++i) {
        const int dqq = half * 4 + i;
        float4 kv = *(const float4*)&k[gbase + dqq * 4];
        Kst[dqq * 4 + 0][rr] = kv.x;
        Kst[dqq * 4 + 1][rr] = kv.y;
        Kst[dqq * 4 + 2][rr] = kv.z;
        Kst[dqq * 4 + 3][rr] = kv.w;
        *(float4*)&LVs[rr][dqq * 4] = *(const float4*)&lv[gbase + dqq * 4];
      }
      if (tid < 128) knS[tid] = kn[bh * Sc + j0g + tid];
    }
    __syncthreads();   // staged tile visible

    // ---- QK: p[2 rows][4 cols] over d=32, 4 b128 per fd-group ----
    float p0[4] = {0.f, 0.f, 0.f, 0.f};
    float p1[4] = {0.f, 0.f, 0.f, 0.f};
#pragma unroll
    for (int fd = 0; fd < 8; ++fd) {
      float4 k0 = *(const float4*)&Kst[fd * 4 + 0][c4 * 4];
      float4 k1 = *(const float4*)&Kst[fd * 4 + 1][c4 * 4];
      float4 k2 = *(const float4*)&Kst[fd * 4 + 2][c4 * 4];
      float4 k3 = *(const float4*)&Kst[fd * 4 + 3][c4 * 4];
      float4 a0 = qv0[fd];
      float4 a1 = qv1[fd];
      p0[0] = fmaf(a0.x, k0.x, p0[0]); p0[0] = fmaf(a0.y, k1.x, p0[0]);
      p0[0] = fmaf(a0.z, k2.x, p0[0]); p0[0] = fmaf(a0.w, k3.x, p0[0]);
      p0[1] = fmaf(a0.x, k0.y, p0[1]); p0[1] = fmaf(a0.y, k1.y, p0[1]);
      p0[1] = fmaf(a0.z, k2.y, p0[1]); p0[1] = fmaf(a0.w, k3.y, p0[1]);
      p0[2] = fmaf(a0.x, k0.z, p0[2]); p0[2] = fmaf(a0.y, k1.z, p0[2]);
      p0[2] = fmaf(a0.z, k2.z, p0[2]); p0[2] = fmaf(a0.w, k3.z, p0[2]);
      p0[3] = fmaf(a0.x, k0.w, p0[3]); p0[3] = fmaf(a0.y, k1.w, p0[3]);
      p0[3] = fmaf(a0.z, k2.w, p0[3]); p0[3] = fmaf(a0.w, k3.w, p0[3]);
      p1[0] = fmaf(a1.x, k0.x, p1[0]); p1[0] = fmaf(a1.y, k1.x, p1[0]);
      p1[0] = fmaf(a1.z, k2.x, p1[0]); p1[0] = fmaf(a1.w, k3.x, p1[0]);
      p1[1] = fmaf(a1.x, k0.y, p1[1]); p1[1] = fmaf(a1.y, k1.y, p1[1]);
      p1[1] = fmaf(a1.z, k2.y, p1[1]); p1[1] = fmaf(a1.w, k3.y, p1[1]);
      p1[2] = fmaf(a1.x, k0.z, p1[2]); p1[2] = fmaf(a1.y, k1.z, p1[2]);
      p1[2] = fmaf(a1.z, k2.z, p1[2]); p1[2] = fmaf(a1.w, k3.z, p1[2]);
      p1[3] = fmaf(a1.x, k0.w, p1[3]); p1[3] = fmaf(a1.y, k1.w, p1[3]);
      p1[3] = fmaf(a1.z, k2.w, p1[3]); p1[3] = fmaf(a1.w, k3.w, p1[3]);
    }

    // ---- epilogue: hyperbolic distance -> p = z^sinv ----
    float4 k2v = *(const float4*)&knS[c4 * 4];
    const float kk2[4] = {k2v.x, k2v.y, k2v.z, k2v.w};
    {
      float po[4];
#pragma unroll
      for (int j = 0; j < 4; ++j) {
        const float k2 = kk2[j];
        const float kq = p0[j];
        const float omk = 1.0f - k2;
        float s2x2 = fmaf(-4.0f, kq, 2.0f * k2 + 2.0f * q20);
        float dden = fmaf(k2, q20, fmaf(-2.0f, kq, 1.0f)) + 1e-15f;
        float Pd = fmaf(dden, omk * omq0, 1e-20f);
        float rp = __builtin_amdgcn_rcpf(Pd);
        float tt = fmaxf(s2x2 * rp, 1e-7f);                    // a-1
        float z = (1.0f + tt) + sqrtf(fmaf(tt, tt, tt + tt));
        po[j] = __builtin_amdgcn_exp2f(sinv * __builtin_amdgcn_logf(z));
      }
      *(float4*)&Pst[2 * r2 + 0][c4 * 4] = make_float4(po[0], po[1], po[2], po[3]);
    }
    {
      float po[4];
#pragma unroll
      for (int j = 0; j < 4; ++j) {
        const float k2 = kk2[j];
        const float kq = p1[j];
        const float omk = 1.0f - k2;
        float s2x2 = fmaf(-4.0f, kq, 2.0f * k2 + 2.0f * q21);
        float dden = fmaf(k2, q21, fmaf(-2.0f, kq, 1.0f)) + 1e-15f;
        float Pd = fmaf(dden, omk * omq1, 1e-20f);
        float rp = __builtin_amdgcn_rcpf(Pd);
        float tt = fmaxf(s2x2 * rp, 1e-7f);
        float z = (1.0f + tt) + sqrtf(fmaf(tt, tt, tt + tt));
        po[j] = __builtin_amdgcn_exp2f(sinv * __builtin_amdgcn_logf(z));
      }
      *(float4*)&Pst[2 * r2 + 1][c4 * 4] = make_float4(po[0], po[1], po[2], po[3]);
    }
    __syncthreads();   // Pst complete

    // ---- PV: acc[4 rows][4 dims] += P[rows][j] * LV[j][dims], j in js-slice
#pragma unroll
    for (int j4 = 0; j4 < 4; ++j4) {
      const int jl = js * 16 + j4 * 4;
      float4 p[4], l[4];
#pragma unroll
      for (int i = 0; i < 4; ++i) p[i] = *(const float4*)&Pst[rg * 4 + i][jl];
#pragma unroll
      for (int c = 0; c < 4; ++c) l[c] = *(const float4*)&LVs[jl + c][dq * 4];
#pragma unroll
      for (int i = 0; i < 4; ++i) {
        lsum4[i] += (p[i].x + p[i].y) + (p[i].z + p[i].w);
        acc[i].x = fmaf(p[i].x, l[0].x, acc[i].x);
        acc[i].y = fmaf(p[i].x, l[0].y, acc[i].y);
        acc[i].z = fmaf(p[i].x, l[0].z, acc[i].z);
        acc[i].w = fmaf(p[i].x, l[0].w, acc[i].w);
        acc[i].x = fmaf(p[i].y, l[1].x, acc[i].x);
        acc[i].y = fmaf(p[i].y, l[1].y, acc[i].y);
        acc[i].z = fmaf(p[i].y, l[1].z, acc[i].z);
        acc[i].w = fmaf(p[i].y, l[1].w, acc[i].w);
        acc[i].x = fmaf(p[i].z, l[2].x, acc[i].x);
        acc[i].y = fmaf(p[i].z, l[2].y, acc[i].y);
        acc[i].z = fmaf(p[i].z, l[2].z, acc[i].z);
        acc[i].w = fmaf(p[i].z, l[2].w, acc[i].w);
        acc[i].x = fmaf(p[i].w, l[3].x, acc[i].x);
        acc[i].y = fmaf(p[i].w, l[3].y, acc[i].y);
        acc[i].z = fmaf(p[i].w, l[3].z, acc[i].z);
        acc[i].w = fmaf(p[i].w, l[3].w, acc[i].w);
      }
    }
    // no trailing barrier: next iteration's top barrier orders restaging
  }

  // ---- merge js partials ----
#pragma unroll
  for (int i = 0; i < 4; ++i)
    *(float4*)&accm[rg * 4 + i][js][dq * 4] = acc[i];
  if (dq == 0) {
#pragma unroll
    for (int i = 0; i < 4; ++i) lsb[rg * 4 + i][js] = lsum4[i];
  }
  __syncthreads();

  const int r2e = tid >> 4;      // 0..15 (row)
  const int dd = tid & 15;       // 0..15, 2 dims each
  float o0 = 0.f, o1 = 0.f, ls = 0.f;
#pragma unroll
  for (int g = 0; g < 8; ++g) {
    float2 a2 = *(const float2*)&accm[r2e][g][dd * 2];
    o0 += a2.x;
    o1 += a2.y;
    ls += lsb[r2e][g];
  }
  const float li = 1.0f / ls;
  o0 *= li;
  o1 *= li;
  float un2 = fmaf(o0, o0, o1 * o1);
#pragma unroll
  for (int m = 8; m >= 1; m >>= 1) un2 += __shfl_xor(un2, m, 16);
  float un = sqrtf(fmaxf(un2, 1e-15f));
  float f = tanh_fast(un) / un;        // expmap0 factor (SC = 1)
  float2 ov = make_float2(o0 * f, o1 * f);
  *(float2*)&out[(size_t)(b * Sc + sq0 + r2e) * Ec + h * Dc + dd * 2] = ov;
}

// ---------------------------------------------------------------------------
// Per-row hyp_linear epilogue for the output projection (sums KSO partials)
// ---------------------------------------------------------------------------
__global__ __launch_bounds__(256) void proj_stats(
    const float* __restrict__ xin, const float* __restrict__ mx,
    const float* __restrict__ bo, float* __restrict__ out) {
  const int t = threadIdx.x;
  const int row = blockIdx.x;
  const size_t idx = (size_t)row * Ec + t;
  const float xv = xin[idx];
  float m = 0.f;
#pragma unroll
  for (int p = 0; p < KSO; ++p) m += mx[idx + (size_t)p * NEc];
  const float bb = bo[t];
  float vals[4] = {xv * xv, m * m, m * bb, bb * bb};
  __shared__ float red[4][4];
  __shared__ float fin[4];
#pragma unroll
  for (int i = 0; i < 4; ++i) {
    float v = fullWaveSum(vals[i]);
    if ((t & 63) == 0) red[i][t >> 6] = v;
  }
  __syncthreads();
  if (t < 4) fin[t] = red[t][0] + red[t][1] + red[t][2] + red[t][3];
  __syncthreads();

  float x2 = fin[0], mx2 = fin[1], mxb = fin[2], b2 = fin[3];
  float xn = sqrtf(fmaxf(x2, 1e-15f));
  float mxn = sqrtf(fmaxf(mx2, 1e-15f));
  float scl = tanh_fast((mxn / xn) * atanh_fast(fminf(xn, MAXNORM))) / mxn;
  float mvv = scl * m;
  float X2 = scl * scl * mx2;
  float XY = scl * mxb;
  float numc = 1.0f + 2.0f * XY + b2;
  float den = 1.0f + 2.0f * XY + X2 * b2 + 1e-15f;
  out[idx] = (numc * mvv + (1.0f - X2) * bb) / den;
}

extern "C" void kernel_launch(void* const* d_in, const int* in_sizes, int n_in,
                              void* d_out, int out_size, void* d_ws, size_t ws_size,
                              hipStream_t stream) {
  (void)in_sizes; (void)n_in; (void)out_size; (void)ws_size;
  const float* x  = (const float*)d_in[0];
  const float* Wq = (const float*)d_in[1];
  const float* bq = (const float*)d_in[2];
  const float* Wk = (const float*)d_in[3];
  const float* bk = (const float*)d_in[4];
  const float* Wv = (const float*)d_in[5];
  const float* bv = (const float*)d_in[6];
  const float* Wo = (const float*)d_in[7];
  const float* bo = (const float*)d_in[8];
  const float* hs = (const float*)d_in[9];

  float* ws = (float*)d_ws;
  const int NE = NEc;            // 262144
  const int NH = NROWS;          // 8192
  float* mxq = ws;               // KSQ*NE partials each
  float* mxk = mxq + KSQ * NE;
  float* mxv = mxk + KSQ * NE;
  float* mxo = mxv + KSQ * NE;   // KSO*NE partials
  float* qb  = mxo + KSO * NE;
  float* kb  = qb + NE;
  float* lvb = kb + NE;
  float* aob = lvb + NE;
  float* qnb = aob + NE;
  float* knb = qnb + NH;

  const int M = Bc * Sc;  // 1024 rows

  gemm_xwt<<<dim3(M / 64, 12, KSQ), 128, 0, stream>>>(x, Wq, Wk, Wv,
                                                      mxq, mxk, mxv, 1);
  qkv_stats<<<M, 256, 0, stream>>>(x, mxq, mxk, mxv, bq, bk, bv,
                                   qb, kb, lvb, qnb, knb);
  attn_fused<<<dim3(32, 16), 256, 0, stream>>>(qb, kb, lvb, qnb, knb, hs, aob);
  gemm_xwt<<<dim3(M / 64, 4, KSO), 128, 0, stream>>>(aob, Wo, Wo, Wo,
                                                     mxo, mxo, mxo, 1);
  proj_stats<<<M, 256, 0, stream>>>(aob, mxo, bo, (float*)d_out);
}